// Round 19
// baseline (156.798 us; speedup 1.0000x reference)
//
#include <hip/hip_runtime.h>
#include <cstddef>

#define N_NODES 12288
#define SIG     2048
#define C1N     16
#define L1N     1024
#define C2N     32
#define F0      64
#define F1      128
#define NEDGE   196608
#define NGRAPH  1024

#define NB_ENC   (N_NODES / 2)                      // encoder blocks (2 nodes each)
#define CNT_BLKS (NEDGE / 256 + N_NODES / 256)      // fused count/cnt blocks
#define C1TW     680                                // c1t words per wave (34 spairs x 20)

typedef float    f32x4 __attribute__((ext_vector_type(4)));
typedef _Float16 f16x8 __attribute__((ext_vector_type(8)));
typedef _Float16 f16x4 __attribute__((ext_vector_type(4)));
typedef __fp16   fp16x2_raw __attribute__((ext_vector_type(2)));   // cvt_pkrtz native type

#if defined(__has_builtin)
#if __has_builtin(__builtin_amdgcn_mfma_f32_16x16x16f16)
#define HAVE_MFMA16 1
#endif
#endif

__device__ __forceinline__ unsigned pkrtz(float a, float b) {    // RTZ pack, 1 inst
    union { fp16x2_raw h; unsigned u; } c;
    c.h = __builtin_amdgcn_cvt_pkrtz(a, b);
    return c.u;
}
__device__ __forceinline__ unsigned pkmax0(unsigned x) {         // packed relu, 1 inst
    unsigned r;
    asm("v_pk_max_f16 %0, %1, 0" : "=v"(r) : "v"(x));
    return r;
}

// ---------------------------------------------------------------- encoder (+fused degree/cnt count)
// R18 encoder + R19 SUB-PHASE REORDER: the zero-barrier design's cost is the
// intra-wave LDS produce->consume chain (5 conv1 tiles then conv2 reads the
// last write; ~4 waves/SIMD can't hide it). Dependences: conv2 nt=0 reads
// slots 0..35 (tiles T0..T2 only); nt=1 reads slots 32..67 (T2..T4). New
// order: T0-T2 -> conv2(nt0) -> T3-T4 -> conv2(nt1) overlaps consumption
// with production. Boundary zeros re-placed to preserve write->read order.
// one block (256 threads = 4 waves) handles TWO nodes: waves 0-1 -> node A,
// waves 2-3 -> node B (hf = wq&1). ZERO hot barriers; 8 sub-phases of 32.
// c1t 34 spairs, wmsum/mean ALIASED onto c1t (cold barrier); conv1 epilogue
// v_pk_max_f16. c1t packing [spair][chq][slot&1] stride 20 words: conv2
// B-frag = 1 ds_read_b128 at cw[20colL+4hi8+320nt+20kt]; conv1 C-frag = 1
// ds_write_b64. conv1 mfma_f32_16x16x16_f16 (K=16; B-frag = 2 ds_read_b32).
// mfma 16x16x32 (m89/m91): A row=l&15,k=(l>>4)*8+j; B col=l&15,same k;
//   C/D col=l&15,row=(l>>4)*4+reg. 16x16x16: same with k=(l>>4)*4+j.
// Lessons: R2/R12/R17 VGPR<=64 everywhere; R5 no stride-4 reads; R9 hot
//   barriers dominate; R10 cvt_pkrtz returns __fp16x2; R16 layout math.
__global__ __launch_bounds__(256) void k_encoder(
    const float* __restrict__ x_raw,
    const float* __restrict__ conv1_w, const float* __restrict__ conv1_b,
    const float* __restrict__ conv2_w, const float* __restrict__ conv2_b,
    const float* __restrict__ lin_w,   const float* __restrict__ lin_b,
    float* __restrict__ h0,
    const int* __restrict__ dst, const int* __restrict__ batch,
    int* __restrict__ deg, float* __restrict__ cnt)
{
    __shared__ __align__(16) unsigned xw[2][1056];     // per-node fp16-pair x
    __shared__ __align__(16) unsigned c1t[4 * C1TW];   // per-wave [34 spair][20 words]
    float* wmsum  = (float*)&c1t[0];                   // ALIAS (after cold barrier): [4][32]
    float* mean_s = (float*)&c1t[128];                 // [2][32]

    const int tid = threadIdx.x;

    // ---- fused degree + graph-node count blocks (early exit, no barriers)
    if (blockIdx.x >= NB_ENC) {
        const int b = blockIdx.x - NB_ENC;
        if (b < NEDGE / 256) {
            atomicAdd(&deg[dst[b * 256 + tid]], 1);
        } else {
            atomicAdd(&cnt[batch[(b - NEDGE / 256) * 256 + tid]], 1.f);
        }
        return;
    }

    const int lane = tid & 63;
    const int wq   = tid >> 6;
    const int colL = lane & 15;
    const int hi8  = lane >> 4;
    const int ndl  = wq >> 1;          // node-local index (0,1)
    const int hf   = wq & 1;           // which 256-output half of the node
    const int node = blockIdx.x * 2 + ndl;
    const float* xrow = x_raw + (size_t)node * SIG;
    unsigned* xn = &xw[ndl][0];

    // ---- stage this wave's x range (RTZ pack). hf0: 136 uint4 -> words [0,544);
    //      hf1: 132 uint4 -> words [512,1040). Word w = {x[2w-8], x[2w-7]}.
    const int nqu = hf ? 132 : 136;
    #pragma unroll
    for (int it = 0; it < 3; ++it) {
        int i = lane + 64 * it;
        if (i < nqu) {
            int xb = 1024 * hf + 8 * i - 8;
            float v[8];
            if (xb >= 0 && xb + 8 <= SIG) {
                float4 xa = *(const float4*)(xrow + xb);
                float4 xc = *(const float4*)(xrow + xb + 4);
                v[0] = xa.x; v[1] = xa.y; v[2] = xa.z; v[3] = xa.w;
                v[4] = xc.x; v[5] = xc.y; v[6] = xc.z; v[7] = xc.w;
            } else {
                #pragma unroll
                for (int t = 0; t < 8; ++t) {
                    int xi = xb + t;
                    v[t] = ((unsigned)xi < (unsigned)SIG) ? xrow[xi] : 0.f;
                }
            }
            uint4 w4;
            w4.x = pkrtz(v[0], v[1]); w4.y = pkrtz(v[2], v[3]);
            w4.z = pkrtz(v[4], v[5]); w4.w = pkrtz(v[6], v[7]);
            *(uint4*)&xn[512 * hf + 4 * i] = w4;
        }
    }
    if (hf == 1 && lane < 16) xn[1040 + lane] = 0u;   // zero tail (reads reach word 1054)

#if HAVE_MFMA16
    // ---- conv1 A fragment (K=16): k=t+1 -> hi8==0 holds k1..3 (taps 0..2),
    //      hi8==1 holds k4..7 (taps 3..6); hi8>=2 zero.
    f16x4 w1A;
    #pragma unroll
    for (int j = 0; j < 4; ++j) w1A[j] = (_Float16)0.f;
    if (hi8 == 0) {
        #pragma unroll
        for (int j = 1; j < 4; ++j) w1A[j] = (_Float16)conv1_w[colL * 7 + (j - 1)];
    } else if (hi8 == 1) {
        #pragma unroll
        for (int j = 0; j < 4; ++j) w1A[j] = (_Float16)conv1_w[colL * 7 + 3 + j];
    }
#else
    f16x8 w1A;
    #pragma unroll
    for (int j = 0; j < 8; ++j) w1A[j] = (_Float16)0.f;
    if (hi8 == 0) {
        #pragma unroll
        for (int j = 1; j < 8; ++j) w1A[j] = (_Float16)conv1_w[colL * 7 + (j - 1)];
    }
#endif
    float bias1[4];
    #pragma unroll
    for (int r = 0; r < 4; ++r) bias1[r] = conv1_b[hi8 * 4 + r];

    // ---- conv2 A fragments: 2 m-tiles x 3 k-tiles; ic=4hi8+(j&3), tap=2kt+(j>>2)
    f16x8 wA[2][3];
    #pragma unroll
    for (int mt = 0; mt < 2; ++mt) {
        const int oc = mt * 16 + colL;
        #pragma unroll
        for (int kt = 0; kt < 3; ++kt) {
            #pragma unroll
            for (int j = 0; j < 8; ++j) {
                const int ic  = 4 * hi8 + (j & 3);
                const int tap = 2 * kt + (j >> 2);
                wA[mt][kt][j] = (_Float16)((tap < 5) ? conv2_w[oc * 80 + ic * 5 + tap] : 0.f);
            }
        }
    }
    float bias2[2][4];
    #pragma unroll
    for (int mt = 0; mt < 2; ++mt)
        #pragma unroll
        for (int r = 0; r < 4; ++r)
            bias2[mt][r] = conv2_b[mt * 16 + hi8 * 4 + r];

    float msumr[2][4];
    #pragma unroll
    for (int mt = 0; mt < 2; ++mt)
        #pragma unroll
        for (int r = 0; r < 4; ++r) msumr[mt][r] = 0.f;

    unsigned* cw = &c1t[wq * C1TW];           // this wave's c1 region (words)
    const int rb = 20 * colL + 4 * hi8;       // lane part of conv2 B word addr

    // ---- 8 sub-phases of 32 conv2 outputs; NO barriers anywhere in this loop
    #pragma unroll 1
    for (int sp = 0; sp < 8; ++sp) {
        const int xwb = 512 * hf + 64 * sp;   // word base within xn

        // conv1 tile: slot = 16T+colL, chq hi8 -> packed c1
        auto do_tile = [&](int T) {
            f32x4 a;
            a[0] = bias1[0]; a[1] = bias1[1]; a[2] = bias1[2]; a[3] = bias1[3];
#if HAVE_MFMA16
            const int wbase = xwb + 16 * T + colL + 2 * hi8;
            union { unsigned u[2]; f16x4 v; } Bx;
            Bx.u[0] = xn[wbase];
            Bx.u[1] = xn[wbase + 1];
            a = __builtin_amdgcn_mfma_f32_16x16x16f16(w1A, Bx.v, a, 0, 0, 0);
#else
            const int wbase = xwb + 16 * T + colL + 4 * hi8;
            union { unsigned u[4]; f16x8 v; } Bx;
            #pragma unroll
            for (int u = 0; u < 4; ++u) Bx.u[u] = xn[wbase + u];
            a = __builtin_amdgcn_mfma_f32_16x16x32_f16(w1A, Bx.v, a, 0, 0, 0);
#endif
            uint2 wr;
            wr.x = pkmax0(pkrtz(a[0], a[1]));   // relu after RTZ == RTZ after relu
            wr.y = pkmax0(pkrtz(a[2], a[3]));
            const int slot = 16 * T + colL;
            if (T < 4 || colL < 4)              // slots >= 68 never read (34-spair buffer)
                *(uint2*)&cw[(slot >> 1) * 20 + 4 * hi8 + (slot & 1) * 2] = wr;
        };
        // conv2 n-tile: 16 outputs (ql = 16nt+colL); B-frag = 1 ds_read_b128
        auto do_nt = [&](int nt) {
            f32x4 acc[2];
            #pragma unroll
            for (int mt = 0; mt < 2; ++mt) {
                acc[mt][0] = bias2[mt][0]; acc[mt][1] = bias2[mt][1];
                acc[mt][2] = bias2[mt][2]; acc[mt][3] = bias2[mt][3];
            }
            #pragma unroll
            for (int kt = 0; kt < 3; ++kt) {
                union { uint4 u4; f16x8 v; } B;
                B.u4 = *(const uint4*)&cw[rb + 320 * nt + 20 * kt];
                #pragma unroll
                for (int mt = 0; mt < 2; ++mt)
                    acc[mt] = __builtin_amdgcn_mfma_f32_16x16x32_f16(wA[mt][kt], B.v, acc[mt], 0, 0, 0);
            }
            #pragma unroll
            for (int mt = 0; mt < 2; ++mt)
                #pragma unroll
                for (int r = 0; r < 4; ++r)
                    msumr[mt][r] += fmaxf(acc[mt][r], 0.f);
        };

        // REORDERED: nt=0 depends on T0..T2 only; nt=1 on T2..T4.
        do_tile(0); do_tile(1); do_tile(2);
        if (hf == 0 && sp == 0) {               // pos -2,-1 -> slots 0,1 -> words 0..15
            if (lane < 16) cw[lane] = 0u;       // after T0, before nt0 reads
        }
        do_nt(0);
        do_tile(3); do_tile(4);
        if (hf == 1 && sp == 7) {               // pos >= 1024 -> slots 66,67 -> spair 33
            if (lane < 20) cw[660 + lane] = 0u; // after T4, before nt1 reads
        }
        do_nt(1);
    }

    // ---- reduce over the 16 columns within each 16-lane group
    #pragma unroll
    for (int mt = 0; mt < 2; ++mt)
        #pragma unroll
        for (int r = 0; r < 4; ++r) {
            float s = msumr[mt][r];
            s += __shfl_xor(s, 1);
            s += __shfl_xor(s, 2);
            s += __shfl_xor(s, 4);
            s += __shfl_xor(s, 8);
            msumr[mt][r] = s;
        }
    __syncthreads();   // ALL waves done with c1t -> alias region safe (cold)
    if (colL == 0) {
        #pragma unroll
        for (int mt = 0; mt < 2; ++mt)
            #pragma unroll
            for (int r = 0; r < 4; ++r)
                wmsum[wq * 32 + mt * 16 + hi8 * 4 + r] = msumr[mt][r];
    }
    __syncthreads();   // wmsum ready (cold)

    if (tid < 64) {    // per-node mean: node nd2 from its 2 waves
        const int nd2 = tid >> 5, oc = tid & 31;
        mean_s[nd2 * 32 + oc] =
            (wmsum[(2 * nd2) * 32 + oc] + wmsum[(2 * nd2 + 1) * 32 + oc]) * (1.f / 512.f);
    }
    __syncthreads();

    // ---- linear 32 -> 64 for both nodes
    if (tid < 128) {
        const int nd2 = tid >> 6, o = tid & 63;
        const int nodew = blockIdx.x * 2 + nd2;
        float a = lin_b[o];
        #pragma unroll
        for (int ic = 0; ic < C2N; ++ic)
            a = fmaf(mean_s[nd2 * 32 + ic], lin_w[ic * F0 + o], a);
        h0[(size_t)nodew * F0 + o] = a;
    }
}

// ---------------------------------------------------------------- scan + dis/invd (1 block, shuffle-based)
__global__ __launch_bounds__(1024) void k_scan(const int* __restrict__ deg,
                                               int* __restrict__ rowptr,
                                               int* __restrict__ cursor,
                                               float* __restrict__ dis,
                                               float* __restrict__ invd)
{
    __shared__ int wtot[16];
    const int t = threadIdx.x;
    const int lane = t & 63, wvid = t >> 6;
    int d[12]; int s = 0;
    #pragma unroll
    for (int m = 0; m < 12; ++m) { d[m] = deg[12 * t + m]; s += d[m]; }
    const int mysum = s;
    #pragma unroll
    for (int off = 1; off < 64; off <<= 1) {
        int u = __shfl_up(s, off);
        if (lane >= off) s += u;
    }
    if (lane == 63) wtot[wvid] = s;
    __syncthreads();
    if (t < 16) {
        int v = wtot[t];
        #pragma unroll
        for (int off = 1; off < 16; off <<= 1) {
            int u = __shfl_up(v, off);
            if (t >= off) v += u;
        }
        wtot[t] = v;
    }
    __syncthreads();
    int run = (wvid ? wtot[wvid - 1] : 0) + (s - mysum);   // block-exclusive prefix
    if (t == 0) rowptr[0] = 0;
    #pragma unroll
    for (int m = 0; m < 12; ++m) {
        const int i = 12 * t + m;
        cursor[i] = run;
        run += d[m];
        rowptr[i + 1] = run;
        float df = (float)(d[m] + 1);
        dis[i]  = rsqrtf(df);
        invd[i] = 1.f / df;
    }
}

// ---------------------------------------------------------------- CSR scatter
__global__ __launch_bounds__(256) void k_scatter(const int* __restrict__ src,
                                                 const int* __restrict__ dst,
                                                 int* __restrict__ cursor,
                                                 int* __restrict__ csr)
{
    int e = blockIdx.x * 256 + threadIdx.x;
    if (e < NEDGE) {
        int d = dst[e];
        int idx = atomicAdd(&cursor[d], 1);
        csr[idx] = src[e];
    }
}

// ---------------------------------------------------------------- fused GCN layer:
// aggregate (pull, no atomics) -> LDS -> @W + bias + relu (+pool)
// agg[n] = invd[n]*h[n] + sum_s dis[s]*dis[n]*h[s]; out = relu(agg@W + b)
// R19: POOL path pre-reduces in LDS (a block's 8 consecutive nodes span <= 2
// graphs since 8 < 12 leads/graph) -> 1 global atomic/thread instead of 4.
template <int K, int POOL>
__global__ __launch_bounds__(256) void k_gcn(
    const float* __restrict__ h, const int* __restrict__ rowptr,
    const int* __restrict__ csr, const float* __restrict__ dis,
    const float* __restrict__ invd, const float* __restrict__ W,
    const float* __restrict__ bvec, float* __restrict__ out,
    const int* __restrict__ batch, float* __restrict__ pooled)
{
    __shared__ float hs[8][K];
    const int tid = threadIdx.x;
    const int n0  = blockIdx.x * 8;

    // ---- aggregation into hs: npb nodes per 256-thread pass
    const int npb = 256 / K;
    const int f   = tid & (K - 1);
    const int sub = tid / K;
    #pragma unroll
    for (int it = 0; it < 8 / npb; ++it) {
        const int nl = it * npb + sub;
        const int n  = n0 + nl;
        const float dn = dis[n];
        float a0 = h[(size_t)n * K + f] * invd[n];
        float a1 = 0.f, a2 = 0.f, a3 = 0.f;
        int e = rowptr[n];
        const int e1 = rowptr[n + 1];
        for (; e + 3 < e1; e += 4) {
            int s0 = csr[e], s1 = csr[e + 1], s2 = csr[e + 2], s3 = csr[e + 3];
            a0 = fmaf(h[(size_t)s0 * K + f], dis[s0] * dn, a0);
            a1 = fmaf(h[(size_t)s1 * K + f], dis[s1] * dn, a1);
            a2 = fmaf(h[(size_t)s2 * K + f], dis[s2] * dn, a2);
            a3 = fmaf(h[(size_t)s3 * K + f], dis[s3] * dn, a3);
        }
        for (; e < e1; ++e) {
            int s0 = csr[e];
            a0 = fmaf(h[(size_t)s0 * K + f], dis[s0] * dn, a0);
        }
        hs[nl][f] = (a0 + a1) + (a2 + a3);
    }
    __syncthreads();

    // ---- GEMM: thread (half=tid>>7, j=tid&127) computes nodes half*4..+3
    const int j    = tid & 127;
    const int half = tid >> 7;
    float a[4];
    #pragma unroll
    for (int c = 0; c < 4; ++c) a[c] = bvec[j];

    for (int k4 = 0; k4 < K; k4 += 4) {
        float w0 = W[(k4 + 0) * F1 + j];
        float w1 = W[(k4 + 1) * F1 + j];
        float w2 = W[(k4 + 2) * F1 + j];
        float w3 = W[(k4 + 3) * F1 + j];
        #pragma unroll
        for (int c = 0; c < 4; ++c) {
            float4 hv = *(const float4*)&hs[half * 4 + c][k4];
            a[c] = fmaf(hv.x, w0, a[c]);
            a[c] = fmaf(hv.y, w1, a[c]);
            a[c] = fmaf(hv.z, w2, a[c]);
            a[c] = fmaf(hv.w, w3, a[c]);
        }
    }

    if constexpr (POOL) {
        __shared__ float pool2[2][F1];
        pool2[tid >> 7][tid & 127] = 0.f;     // 256 threads cover [2][128]
        __syncthreads();
        const int gbase = batch[n0];
        #pragma unroll
        for (int c = 0; c < 4; ++c) {
            float r = fmaxf(a[c], 0.f);
            int n = n0 + half * 4 + c;
            int idx = batch[n] - gbase;       // 0 or 1 (8 nodes span <= 2 graphs)
            atomicAdd(&pool2[idx][j], r);     // LDS atomic, 2-way contention
        }
        __syncthreads();
        const int gi = tid >> 7, jj = tid & 127;
        const int g  = gbase + gi;
        if (g < NGRAPH)
            atomicAdd(&pooled[(size_t)g * F1 + jj], pool2[gi][jj]);
    } else {
        #pragma unroll
        for (int c = 0; c < 4; ++c) {
            float r = fmaxf(a[c], 0.f);
            int n = n0 + half * 4 + c;
            out[(size_t)n * F1 + j] = r;
        }
    }
}

// ---------------------------------------------------------------- final FC 128 -> 5
__global__ __launch_bounds__(128) void k_final(const float* __restrict__ pooled,
                                               const float* __restrict__ cnt,
                                               const float* __restrict__ fc_w,
                                               const float* __restrict__ fc_b,
                                               float* __restrict__ out)
{
    __shared__ float ps[F1];
    const int g = blockIdx.x, tid = threadIdx.x;
    float inv = 1.f / fmaxf(cnt[g], 1.f);
    ps[tid] = pooled[g * F1 + tid] * inv;
    __syncthreads();
    if (tid < 5) {
        float a = fc_b[tid];
        for (int f = 0; f < F1; ++f) a = fmaf(ps[f], fc_w[f * 5 + tid], a);
        out[g * 5 + tid] = a;
    }
}

// ---------------------------------------------------------------- launch
extern "C" void kernel_launch(void* const* d_in, const int* in_sizes, int n_in,
                              void* d_out, int out_size, void* d_ws, size_t ws_size,
                              hipStream_t stream)
{
    const float* x_raw = (const float*)d_in[0];
    const float* c1w   = (const float*)d_in[1];
    const float* c1b   = (const float*)d_in[2];
    const float* c2w   = (const float*)d_in[3];
    const float* c2b   = (const float*)d_in[4];
    const float* lw    = (const float*)d_in[5];
    const float* lb    = (const float*)d_in[6];
    const float* g1w   = (const float*)d_in[7];
    const float* g1b   = (const float*)d_in[8];
    const float* g2w   = (const float*)d_in[9];
    const float* g2b   = (const float*)d_in[10];
    const float* fcw   = (const float*)d_in[11];
    const float* fcb   = (const float*)d_in[12];
    const int*   ei    = (const int*)d_in[13];
    const int*   batch = (const int*)d_in[14];
    const int* src = ei;
    const int* dst = ei + NEDGE;

    float* ws = (float*)d_ws;
    float* h0     = ws + 0;                    // 786432  (12288 x 64)
    float* h1     = ws + 786432;               // 1572864 (12288 x 128)
    float* dis    = ws + 2359296;              // 12288
    float* invd   = ws + 2371584;              // 12288
    float* pooled = ws + 2383872;              // 131072
    float* cnt    = ws + 2514944;              // 1024 (contiguous after pooled)
    int*   deg    = (int*)(ws + 2515968);      // 12288
    int*   rowptr = (int*)(ws + 2528256);      // 12289 (+pad)
    int*   cursor = (int*)(ws + 2540548);      // 12288
    int*   csr    = (int*)(ws + 2552836);      // 196608

    float* out = (float*)d_out;

    hipMemsetAsync(deg, 0, N_NODES * sizeof(int), stream);
    hipMemsetAsync(pooled, 0, (size_t)(NGRAPH * F1 + NGRAPH) * sizeof(float), stream);

    // encoder (2 nodes/block) + fused degree/graph-count blocks
    k_encoder<<<NB_ENC + CNT_BLKS, 256, 0, stream>>>(
        x_raw, c1w, c1b, c2w, c2b, lw, lb, h0, dst, batch, deg, cnt);
    k_scan<<<1, 1024, 0, stream>>>(deg, rowptr, cursor, dis, invd);
    k_scatter<<<NEDGE / 256, 256, 0, stream>>>(src, dst, cursor, csr);

    // GCN layer 1 (fused aggregate + transform)
    k_gcn<F0, 0><<<N_NODES / 8, 256, 0, stream>>>(h0, rowptr, csr, dis, invd, g1w, g1b, h1, batch, pooled);
    // GCN layer 2 (fused aggregate + transform + LDS-pooled graph mean)
    k_gcn<F1, 1><<<N_NODES / 8, 256, 0, stream>>>(h1, rowptr, csr, dis, invd, g2w, g2b, nullptr, batch, pooled);

    k_final<<<NGRAPH, 128, 0, stream>>>(pooled, cnt, fcw, fcb, out);
}

// Round 20
// 149.653 us; speedup vs baseline: 1.0477x; 1.0477x over previous
//
#include <hip/hip_runtime.h>
#include <cstddef>

#define N_NODES 12288
#define SIG     2048
#define C1N     16
#define L1N     1024
#define C2N     32
#define F0      64
#define F1      128
#define NEDGE   196608
#define NGRAPH  1024

#define NB_ENC   (N_NODES / 2)                      // encoder blocks (2 nodes each)
#define CNT_BLKS (NEDGE / 256 + N_NODES / 256)      // fused count/cnt blocks
#define C1TW     680                                // c1t words per wave (34 spairs x 20)

typedef float    f32x4 __attribute__((ext_vector_type(4)));
typedef _Float16 f16x8 __attribute__((ext_vector_type(8)));
typedef _Float16 f16x4 __attribute__((ext_vector_type(4)));
typedef __fp16   fp16x2_raw __attribute__((ext_vector_type(2)));   // cvt_pkrtz native type

#if defined(__has_builtin)
#if __has_builtin(__builtin_amdgcn_mfma_f32_16x16x16f16)
#define HAVE_MFMA16 1
#endif
#endif

__device__ __forceinline__ unsigned pkrtz(float a, float b) {    // RTZ pack, 1 inst
    union { fp16x2_raw h; unsigned u; } c;
    c.h = __builtin_amdgcn_cvt_pkrtz(a, b);
    return c.u;
}
__device__ __forceinline__ unsigned pkmax0(unsigned x) {         // packed relu, 1 inst
    unsigned r;
    asm("v_pk_max_f16 %0, %1, 0" : "=v"(r) : "v"(x));
    return r;
}

// ---------------------------------------------------------------- encoder (+fused degree/cnt count)
// R18 encoder EXACTLY (best known: 90us, LDS 19456 -> 8 blocks/CU, VGPR 48).
// R19 lessons: sub-phase reorder NEUTRAL (chain already hidden by 8-wave
// residency + compiler scheduling); LDS pre-pooled k_gcn slightly NEGATIVE.
// At ~80% combined pipe occupancy only instruction-count or residency
// changes move this kernel — scheduling tweaks are noise.
// one block (256 threads = 4 waves) handles TWO nodes: waves 0-1 -> node A,
// waves 2-3 -> node B (hf = wq&1). ZERO hot barriers; 8 sub-phases of 32.
// c1t 34 spairs, wmsum/mean ALIASED onto c1t (cold barrier); conv1 epilogue
// v_pk_max_f16 (bit-identical to fmax-then-pkrtz).
// c1t packing [spair][chq][slot&1] stride 20 words: conv2 B-frag = 1
// ds_read_b128 at cw[20colL+4hi8+320nt+20kt]; conv1 C-frag = 1 ds_write_b64.
// conv1 mfma_f32_16x16x16_f16 (K=16; B-frag = 2 ds_read_b32).
// mfma 16x16x32 (m89/m91): A row=l&15,k=(l>>4)*8+j; B col=l&15,same k;
//   C/D col=l&15,row=(l>>4)*4+reg. 16x16x16: same with k=(l>>4)*4+j.
// Lessons: R2/R12/R17 VGPR<=64 everywhere; R5 no stride-4 reads; R9 hot
//   barriers dominate; R10 cvt_pkrtz returns __fp16x2; R16 layout math.
__global__ __launch_bounds__(256) void k_encoder(
    const float* __restrict__ x_raw,
    const float* __restrict__ conv1_w, const float* __restrict__ conv1_b,
    const float* __restrict__ conv2_w, const float* __restrict__ conv2_b,
    const float* __restrict__ lin_w,   const float* __restrict__ lin_b,
    float* __restrict__ h0,
    const int* __restrict__ dst, const int* __restrict__ batch,
    int* __restrict__ deg, float* __restrict__ cnt)
{
    __shared__ __align__(16) unsigned xw[2][1056];     // per-node fp16-pair x
    __shared__ __align__(16) unsigned c1t[4 * C1TW];   // per-wave [34 spair][20 words]
    float* wmsum  = (float*)&c1t[0];                   // ALIAS (after cold barrier): [4][32]
    float* mean_s = (float*)&c1t[128];                 // [2][32]

    const int tid = threadIdx.x;

    // ---- fused degree + graph-node count blocks (early exit, no barriers)
    if (blockIdx.x >= NB_ENC) {
        const int b = blockIdx.x - NB_ENC;
        if (b < NEDGE / 256) {
            atomicAdd(&deg[dst[b * 256 + tid]], 1);
        } else {
            atomicAdd(&cnt[batch[(b - NEDGE / 256) * 256 + tid]], 1.f);
        }
        return;
    }

    const int lane = tid & 63;
    const int wq   = tid >> 6;
    const int colL = lane & 15;
    const int hi8  = lane >> 4;
    const int ndl  = wq >> 1;          // node-local index (0,1)
    const int hf   = wq & 1;           // which 256-output half of the node
    const int node = blockIdx.x * 2 + ndl;
    const float* xrow = x_raw + (size_t)node * SIG;
    unsigned* xn = &xw[ndl][0];

    // ---- stage this wave's x range (RTZ pack). hf0: 136 uint4 -> words [0,544);
    //      hf1: 132 uint4 -> words [512,1040). Word w = {x[2w-8], x[2w-7]}.
    const int nqu = hf ? 132 : 136;
    #pragma unroll
    for (int it = 0; it < 3; ++it) {
        int i = lane + 64 * it;
        if (i < nqu) {
            int xb = 1024 * hf + 8 * i - 8;
            float v[8];
            if (xb >= 0 && xb + 8 <= SIG) {
                float4 xa = *(const float4*)(xrow + xb);
                float4 xc = *(const float4*)(xrow + xb + 4);
                v[0] = xa.x; v[1] = xa.y; v[2] = xa.z; v[3] = xa.w;
                v[4] = xc.x; v[5] = xc.y; v[6] = xc.z; v[7] = xc.w;
            } else {
                #pragma unroll
                for (int t = 0; t < 8; ++t) {
                    int xi = xb + t;
                    v[t] = ((unsigned)xi < (unsigned)SIG) ? xrow[xi] : 0.f;
                }
            }
            uint4 w4;
            w4.x = pkrtz(v[0], v[1]); w4.y = pkrtz(v[2], v[3]);
            w4.z = pkrtz(v[4], v[5]); w4.w = pkrtz(v[6], v[7]);
            *(uint4*)&xn[512 * hf + 4 * i] = w4;
        }
    }
    if (hf == 1 && lane < 16) xn[1040 + lane] = 0u;   // zero tail (reads reach word 1054)

#if HAVE_MFMA16
    // ---- conv1 A fragment (K=16): k=t+1 -> hi8==0 holds k1..3 (taps 0..2),
    //      hi8==1 holds k4..7 (taps 3..6); hi8>=2 zero.
    f16x4 w1A;
    #pragma unroll
    for (int j = 0; j < 4; ++j) w1A[j] = (_Float16)0.f;
    if (hi8 == 0) {
        #pragma unroll
        for (int j = 1; j < 4; ++j) w1A[j] = (_Float16)conv1_w[colL * 7 + (j - 1)];
    } else if (hi8 == 1) {
        #pragma unroll
        for (int j = 0; j < 4; ++j) w1A[j] = (_Float16)conv1_w[colL * 7 + 3 + j];
    }
#else
    f16x8 w1A;
    #pragma unroll
    for (int j = 0; j < 8; ++j) w1A[j] = (_Float16)0.f;
    if (hi8 == 0) {
        #pragma unroll
        for (int j = 1; j < 8; ++j) w1A[j] = (_Float16)conv1_w[colL * 7 + (j - 1)];
    }
#endif
    float bias1[4];
    #pragma unroll
    for (int r = 0; r < 4; ++r) bias1[r] = conv1_b[hi8 * 4 + r];

    // ---- conv2 A fragments: 2 m-tiles x 3 k-tiles; ic=4hi8+(j&3), tap=2kt+(j>>2)
    f16x8 wA[2][3];
    #pragma unroll
    for (int mt = 0; mt < 2; ++mt) {
        const int oc = mt * 16 + colL;
        #pragma unroll
        for (int kt = 0; kt < 3; ++kt) {
            #pragma unroll
            for (int j = 0; j < 8; ++j) {
                const int ic  = 4 * hi8 + (j & 3);
                const int tap = 2 * kt + (j >> 2);
                wA[mt][kt][j] = (_Float16)((tap < 5) ? conv2_w[oc * 80 + ic * 5 + tap] : 0.f);
            }
        }
    }
    float bias2[2][4];
    #pragma unroll
    for (int mt = 0; mt < 2; ++mt)
        #pragma unroll
        for (int r = 0; r < 4; ++r)
            bias2[mt][r] = conv2_b[mt * 16 + hi8 * 4 + r];

    float msumr[2][4];
    #pragma unroll
    for (int mt = 0; mt < 2; ++mt)
        #pragma unroll
        for (int r = 0; r < 4; ++r) msumr[mt][r] = 0.f;

    unsigned* cw = &c1t[wq * C1TW];           // this wave's c1 region (words)
    const int rb = 20 * colL + 4 * hi8;       // lane part of conv2 B word addr

    // ---- 8 sub-phases of 32 conv2 outputs; NO barriers anywhere in this loop
    #pragma unroll 1
    for (int sp = 0; sp < 8; ++sp) {
        const int xwb = 512 * hf + 64 * sp;   // word base within xn

        // conv1: 5 pos-tiles of 16 -> packed c1 (slot = 16T+colL, chq hi8)
        #pragma unroll
        for (int T = 0; T < 5; ++T) {
            f32x4 a;
            a[0] = bias1[0]; a[1] = bias1[1]; a[2] = bias1[2]; a[3] = bias1[3];
#if HAVE_MFMA16
            const int wbase = xwb + 16 * T + colL + 2 * hi8;
            union { unsigned u[2]; f16x4 v; } Bx;
            Bx.u[0] = xn[wbase];
            Bx.u[1] = xn[wbase + 1];
            a = __builtin_amdgcn_mfma_f32_16x16x16f16(w1A, Bx.v, a, 0, 0, 0);
#else
            const int wbase = xwb + 16 * T + colL + 4 * hi8;
            union { unsigned u[4]; f16x8 v; } Bx;
            #pragma unroll
            for (int u = 0; u < 4; ++u) Bx.u[u] = xn[wbase + u];
            a = __builtin_amdgcn_mfma_f32_16x16x32_f16(w1A, Bx.v, a, 0, 0, 0);
#endif
            uint2 wr;
            wr.x = pkmax0(pkrtz(a[0], a[1]));   // relu after RTZ == RTZ after relu
            wr.y = pkmax0(pkrtz(a[2], a[3]));
            const int slot = 16 * T + colL;
            if (T < 4 || colL < 4)              // slots >= 68 never read (34-spair buffer)
                *(uint2*)&cw[(slot >> 1) * 20 + 4 * hi8 + (slot & 1) * 2] = wr;
        }
        // boundary fix: zero c1 slots whose node position is outside [0,1024)
        if (hf == 0 && sp == 0) {               // pos -2,-1 -> slots 0,1 -> words 0..15
            if (lane < 16) cw[lane] = 0u;
        }
        if (hf == 1 && sp == 7) {               // pos >= 1024 -> slots 66,67 -> spair 33
            if (lane < 20) cw[660 + lane] = 0u;
        }

        // conv2: 2 n-tiles of 16 outputs (ql = 16nt+colL); B-frag = 1 ds_read_b128
        #pragma unroll
        for (int nt = 0; nt < 2; ++nt) {
            f32x4 acc[2];
            #pragma unroll
            for (int mt = 0; mt < 2; ++mt) {
                acc[mt][0] = bias2[mt][0]; acc[mt][1] = bias2[mt][1];
                acc[mt][2] = bias2[mt][2]; acc[mt][3] = bias2[mt][3];
            }
            #pragma unroll
            for (int kt = 0; kt < 3; ++kt) {
                union { uint4 u4; f16x8 v; } B;
                B.u4 = *(const uint4*)&cw[rb + 320 * nt + 20 * kt];
                #pragma unroll
                for (int mt = 0; mt < 2; ++mt)
                    acc[mt] = __builtin_amdgcn_mfma_f32_16x16x32_f16(wA[mt][kt], B.v, acc[mt], 0, 0, 0);
            }
            #pragma unroll
            for (int mt = 0; mt < 2; ++mt)
                #pragma unroll
                for (int r = 0; r < 4; ++r)
                    msumr[mt][r] += fmaxf(acc[mt][r], 0.f);
        }
    }

    // ---- reduce over the 16 columns within each 16-lane group
    #pragma unroll
    for (int mt = 0; mt < 2; ++mt)
        #pragma unroll
        for (int r = 0; r < 4; ++r) {
            float s = msumr[mt][r];
            s += __shfl_xor(s, 1);
            s += __shfl_xor(s, 2);
            s += __shfl_xor(s, 4);
            s += __shfl_xor(s, 8);
            msumr[mt][r] = s;
        }
    __syncthreads();   // ALL waves done with c1t -> alias region safe (cold)
    if (colL == 0) {
        #pragma unroll
        for (int mt = 0; mt < 2; ++mt)
            #pragma unroll
            for (int r = 0; r < 4; ++r)
                wmsum[wq * 32 + mt * 16 + hi8 * 4 + r] = msumr[mt][r];
    }
    __syncthreads();   // wmsum ready (cold)

    if (tid < 64) {    // per-node mean: node nd2 from its 2 waves
        const int nd2 = tid >> 5, oc = tid & 31;
        mean_s[nd2 * 32 + oc] =
            (wmsum[(2 * nd2) * 32 + oc] + wmsum[(2 * nd2 + 1) * 32 + oc]) * (1.f / 512.f);
    }
    __syncthreads();

    // ---- linear 32 -> 64 for both nodes
    if (tid < 128) {
        const int nd2 = tid >> 6, o = tid & 63;
        const int nodew = blockIdx.x * 2 + nd2;
        float a = lin_b[o];
        #pragma unroll
        for (int ic = 0; ic < C2N; ++ic)
            a = fmaf(mean_s[nd2 * 32 + ic], lin_w[ic * F0 + o], a);
        h0[(size_t)nodew * F0 + o] = a;
    }
}

// ---------------------------------------------------------------- scan + dis/invd (1 block, shuffle-based)
__global__ __launch_bounds__(1024) void k_scan(const int* __restrict__ deg,
                                               int* __restrict__ rowptr,
                                               int* __restrict__ cursor,
                                               float* __restrict__ dis,
                                               float* __restrict__ invd)
{
    __shared__ int wtot[16];
    const int t = threadIdx.x;
    const int lane = t & 63, wvid = t >> 6;
    int d[12]; int s = 0;
    #pragma unroll
    for (int m = 0; m < 12; ++m) { d[m] = deg[12 * t + m]; s += d[m]; }
    const int mysum = s;
    #pragma unroll
    for (int off = 1; off < 64; off <<= 1) {
        int u = __shfl_up(s, off);
        if (lane >= off) s += u;
    }
    if (lane == 63) wtot[wvid] = s;
    __syncthreads();
    if (t < 16) {
        int v = wtot[t];
        #pragma unroll
        for (int off = 1; off < 16; off <<= 1) {
            int u = __shfl_up(v, off);
            if (t >= off) v += u;
        }
        wtot[t] = v;
    }
    __syncthreads();
    int run = (wvid ? wtot[wvid - 1] : 0) + (s - mysum);   // block-exclusive prefix
    if (t == 0) rowptr[0] = 0;
    #pragma unroll
    for (int m = 0; m < 12; ++m) {
        const int i = 12 * t + m;
        cursor[i] = run;
        run += d[m];
        rowptr[i + 1] = run;
        float df = (float)(d[m] + 1);
        dis[i]  = rsqrtf(df);
        invd[i] = 1.f / df;
    }
}

// ---------------------------------------------------------------- CSR scatter
__global__ __launch_bounds__(256) void k_scatter(const int* __restrict__ src,
                                                 const int* __restrict__ dst,
                                                 int* __restrict__ cursor,
                                                 int* __restrict__ csr)
{
    int e = blockIdx.x * 256 + threadIdx.x;
    if (e < NEDGE) {
        int d = dst[e];
        int idx = atomicAdd(&cursor[d], 1);
        csr[idx] = src[e];
    }
}

// ---------------------------------------------------------------- fused GCN layer (R15/R18-proven):
// aggregate (pull, no atomics) -> LDS -> @W + bias + relu (+pool)
// agg[n] = invd[n]*h[n] + sum_s dis[s]*dis[n]*h[s]; out = relu(agg@W + b)
template <int K, int POOL>
__global__ __launch_bounds__(256) void k_gcn(
    const float* __restrict__ h, const int* __restrict__ rowptr,
    const int* __restrict__ csr, const float* __restrict__ dis,
    const float* __restrict__ invd, const float* __restrict__ W,
    const float* __restrict__ bvec, float* __restrict__ out,
    const int* __restrict__ batch, float* __restrict__ pooled)
{
    __shared__ float hs[8][K];
    const int tid = threadIdx.x;
    const int n0  = blockIdx.x * 8;

    // ---- aggregation into hs: npb nodes per 256-thread pass
    const int npb = 256 / K;
    const int f   = tid & (K - 1);
    const int sub = tid / K;
    #pragma unroll
    for (int it = 0; it < 8 / npb; ++it) {
        const int nl = it * npb + sub;
        const int n  = n0 + nl;
        const float dn = dis[n];
        float a0 = h[(size_t)n * K + f] * invd[n];
        float a1 = 0.f, a2 = 0.f, a3 = 0.f;
        int e = rowptr[n];
        const int e1 = rowptr[n + 1];
        for (; e + 3 < e1; e += 4) {
            int s0 = csr[e], s1 = csr[e + 1], s2 = csr[e + 2], s3 = csr[e + 3];
            a0 = fmaf(h[(size_t)s0 * K + f], dis[s0] * dn, a0);
            a1 = fmaf(h[(size_t)s1 * K + f], dis[s1] * dn, a1);
            a2 = fmaf(h[(size_t)s2 * K + f], dis[s2] * dn, a2);
            a3 = fmaf(h[(size_t)s3 * K + f], dis[s3] * dn, a3);
        }
        for (; e < e1; ++e) {
            int s0 = csr[e];
            a0 = fmaf(h[(size_t)s0 * K + f], dis[s0] * dn, a0);
        }
        hs[nl][f] = (a0 + a1) + (a2 + a3);
    }
    __syncthreads();

    // ---- GEMM: thread (half=tid>>7, j=tid&127) computes nodes half*4..+3
    const int j    = tid & 127;
    const int half = tid >> 7;
    float a[4];
    #pragma unroll
    for (int c = 0; c < 4; ++c) a[c] = bvec[j];

    for (int k4 = 0; k4 < K; k4 += 4) {
        float w0 = W[(k4 + 0) * F1 + j];
        float w1 = W[(k4 + 1) * F1 + j];
        float w2 = W[(k4 + 2) * F1 + j];
        float w3 = W[(k4 + 3) * F1 + j];
        #pragma unroll
        for (int c = 0; c < 4; ++c) {
            float4 hv = *(const float4*)&hs[half * 4 + c][k4];
            a[c] = fmaf(hv.x, w0, a[c]);
            a[c] = fmaf(hv.y, w1, a[c]);
            a[c] = fmaf(hv.z, w2, a[c]);
            a[c] = fmaf(hv.w, w3, a[c]);
        }
    }
    #pragma unroll
    for (int c = 0; c < 4; ++c) {
        float r = fmaxf(a[c], 0.f);
        int n = n0 + half * 4 + c;
        if (POOL) atomicAdd(&pooled[(size_t)batch[n] * F1 + j], r);
        else      out[(size_t)n * F1 + j] = r;
    }
}

// ---------------------------------------------------------------- final FC 128 -> 5
__global__ __launch_bounds__(128) void k_final(const float* __restrict__ pooled,
                                               const float* __restrict__ cnt,
                                               const float* __restrict__ fc_w,
                                               const float* __restrict__ fc_b,
                                               float* __restrict__ out)
{
    __shared__ float ps[F1];
    const int g = blockIdx.x, tid = threadIdx.x;
    float inv = 1.f / fmaxf(cnt[g], 1.f);
    ps[tid] = pooled[g * F1 + tid] * inv;
    __syncthreads();
    if (tid < 5) {
        float a = fc_b[tid];
        for (int f = 0; f < F1; ++f) a = fmaf(ps[f], fc_w[f * 5 + tid], a);
        out[g * 5 + tid] = a;
    }
}

// ---------------------------------------------------------------- launch
extern "C" void kernel_launch(void* const* d_in, const int* in_sizes, int n_in,
                              void* d_out, int out_size, void* d_ws, size_t ws_size,
                              hipStream_t stream)
{
    const float* x_raw = (const float*)d_in[0];
    const float* c1w   = (const float*)d_in[1];
    const float* c1b   = (const float*)d_in[2];
    const float* c2w   = (const float*)d_in[3];
    const float* c2b   = (const float*)d_in[4];
    const float* lw    = (const float*)d_in[5];
    const float* lb    = (const float*)d_in[6];
    const float* g1w   = (const float*)d_in[7];
    const float* g1b   = (const float*)d_in[8];
    const float* g2w   = (const float*)d_in[9];
    const float* g2b   = (const float*)d_in[10];
    const float* fcw   = (const float*)d_in[11];
    const float* fcb   = (const float*)d_in[12];
    const int*   ei    = (const int*)d_in[13];
    const int*   batch = (const int*)d_in[14];
    const int* src = ei;
    const int* dst = ei + NEDGE;

    // workspace layout: pooled, cnt, deg CONTIGUOUS so one memset zeros all three.
    float* ws = (float*)d_ws;
    float* h0     = ws + 0;                    // 786432  (12288 x 64)
    float* h1     = ws + 786432;               // 1572864 (12288 x 128)
    float* dis    = ws + 2359296;              // 12288
    float* invd   = ws + 2371584;              // 12288
    float* pooled = ws + 2383872;              // 131072
    float* cnt    = ws + 2514944;              // 1024
    int*   deg    = (int*)(ws + 2515968);      // 12288
    int*   rowptr = (int*)(ws + 2528256);      // 12289 (+pad)
    int*   cursor = (int*)(ws + 2540548);      // 12288
    int*   csr    = (int*)(ws + 2552836);      // 196608

    float* out = (float*)d_out;

    // single memset covers pooled + cnt + deg (contiguous, 144384 words)
    hipMemsetAsync(pooled, 0, (size_t)(NGRAPH * F1 + NGRAPH + N_NODES) * sizeof(float), stream);

    // encoder (2 nodes/block) + fused degree/graph-count blocks
    k_encoder<<<NB_ENC + CNT_BLKS, 256, 0, stream>>>(
        x_raw, c1w, c1b, c2w, c2b, lw, lb, h0, dst, batch, deg, cnt);
    k_scan<<<1, 1024, 0, stream>>>(deg, rowptr, cursor, dis, invd);
    k_scatter<<<NEDGE / 256, 256, 0, stream>>>(src, dst, cursor, csr);

    // GCN layer 1 (fused aggregate + transform)
    k_gcn<F0, 0><<<N_NODES / 8, 256, 0, stream>>>(h0, rowptr, csr, dis, invd, g1w, g1b, h1, batch, pooled);
    // GCN layer 2 (fused aggregate + transform + pool)
    k_gcn<F1, 1><<<N_NODES / 8, 256, 0, stream>>>(h1, rowptr, csr, dis, invd, g2w, g2b, nullptr, batch, pooled);

    k_final<<<NGRAPH, 128, 0, stream>>>(pooled, cnt, fcw, fcb, out);
}